// Round 6
// baseline (1471.599 us; speedup 1.0000x reference)
//
#include <hip/hip_runtime.h>

#define Bn 32
#define Kn 512
#define Cn 32

typedef float vf4 __attribute__((ext_vector_type(4)));

// ws layout
#define WTC_OFF   0          // 16384 floats: w_col transposed  wTc[k*32+o]
#define WTR_OFF   16384      // 16384 floats: w_row transposed
#define PART_OFF  32768      // 32*8*32 floats: part[b][chunk][o] (bias included)
#define FLAG_OFF  40960      // 32*8 uints: flag[b*8+chunk]
#define MAGIC     0x5ADF00D1u

// ---------------- k0: transpose weights to k-major ----------------
__global__ void k_prep(const float* __restrict__ w_col,
                       const float* __restrict__ w_row,
                       float* __restrict__ ws) {
    int idx = blockIdx.x * 256 + threadIdx.x;          // 0..32767
    int which = idx >> 14;                             // 0: col, 1: row
    int e = idx & 16383;
    int o = e & 31, k = e >> 5;
    const float* src = which ? w_row : w_col;
    float* dst = ws + (which ? WTR_OFF : WTC_OFF);
    dst[e] = src[o * Kn + k];
}

// ---------------- k1: producer-consumer mega-kernel ----------------
// grid 8448 × 512 threads.
// bids 0..255   (dispatched FIRST): compute block (chunk=bid&7, b=bid>>3) —
//               round-5 hot loop, publishes part[b][chunk][0..31] + MAGIC flag.
// bids 256..8447: broadcast block (bo=(bid-256)>>3, oct=(bid-256)&7) — polls the
//               8 flags of its b, sums partials, streams 128 KB of output.
__global__ __launch_bounds__(512) void k_mega(
    const float* __restrict__ x,      // [B][K][K]
    const float* __restrict__ bcol,
    const float* __restrict__ brow,
    float* __restrict__ ws,
    float* __restrict__ out) {
    __shared__ float buf[8][64 * 33]; // 67.6 KB
    __shared__ float red2[16 * 33];
    unsigned* __restrict__ wsu = (unsigned*)ws;
    const int bid = blockIdx.x;
    const int tid = threadIdx.x;

    if (bid < 256) {
        // ---------------- producer: col/row GEMMs + dot-reduce ----------------
        const int chunk = bid & 7;
        const int b     = bid >> 3;
        const int t0  = chunk * 64;
        const int t   = tid & 63;                                   // lane
        const int wv  = __builtin_amdgcn_readfirstlane(tid >> 6);   // 0..7
        const int phase = wv >> 2;
        const int kh    = wv & 3;

        const float* __restrict__ xb = x + b * (Kn * Kn);

        float acc[32];
#pragma unroll
        for (int o = 0; o < 32; ++o) acc[o] = 0.f;

        if (phase == 0) {
            // col[t,o] = sum_k x[t0+t][k] * wTc[k][o] — per-thread contiguous rows
            const float4* __restrict__ xr = (const float4*)(xb + (t0 + t) * Kn) + kh * 32;
            const float* __restrict__ wk = ws + WTC_OFF + kh * 128 * 32;
#pragma unroll 2
            for (int j = 0; j < 32; ++j) {                 // 32 float4 = 128 k
                float4 v = xr[j];
                const float* __restrict__ w0 = wk + j * 128;   // uniform → s_load
#pragma unroll
                for (int o = 0; o < 32; ++o) acc[o] = fmaf(v.x, w0[o],      acc[o]);
#pragma unroll
                for (int o = 0; o < 32; ++o) acc[o] = fmaf(v.y, w0[32 + o], acc[o]);
#pragma unroll
                for (int o = 0; o < 32; ++o) acc[o] = fmaf(v.z, w0[64 + o], acc[o]);
#pragma unroll
                for (int o = 0; o < 32; ++o) acc[o] = fmaf(v.w, w0[96 + o], acc[o]);
            }
        } else {
            // row[t,o] = sum_k x[k][t0+t] * wTr[k][o] — lane-contiguous column reads
            const float* __restrict__ wr = ws + WTR_OFF;
            const int kb = kh * 128;
#pragma unroll 4
            for (int k = 0; k < 128; ++k) {
                float xv = xb[(kb + k) * Kn + t0 + t];
                const float* __restrict__ w = wr + (kb + k) * 32;  // uniform → s_load
#pragma unroll
                for (int o = 0; o < 32; ++o) acc[o] = fmaf(xv, w[o], acc[o]);
            }
        }

        // park all 8 wave-accumulators in LDS ((33t+o)%32 = (t+o)%32, clean)
        {
            float* __restrict__ my = buf[wv] + t * 33;
#pragma unroll
            for (int o = 0; o < 32; ++o) my[o] = acc[o];
        }
        __syncthreads();

        // product-reduce: o = tid&31, g = tid>>5 covers 4 t each
        const int o = tid & 31, g = tid >> 5;            // g: 0..15
        const float bc = bcol[o], br = brow[o];
        float sum = 0.f;
#pragma unroll
        for (int j = 0; j < 4; ++j) {
            const int tt = g * 4 + j;
            const int a  = tt * 33 + o;
            float c = buf[0][a] + buf[1][a] + buf[2][a] + buf[3][a] + bc;
            float r = buf[4][a] + buf[5][a] + buf[6][a] + buf[7][a] + br;
            sum = fmaf(c, r, sum);
        }
        red2[g * 33 + o] = sum;
        __syncthreads();
        if (tid < 32) {
            float s = 0.f;
#pragma unroll
            for (int j = 0; j < 16; ++j) s += red2[j * 33 + tid];
            __hip_atomic_store(ws + PART_OFF + (b * 8 + chunk) * 32 + tid, s,
                               __ATOMIC_RELAXED, __HIP_MEMORY_SCOPE_AGENT);
        }
        if (tid == 0) {
            __threadfence();   // drain wave's part stores, agent visibility
            __hip_atomic_store(wsu + FLAG_OFF + b * 8 + chunk, MAGIC,
                               __ATOMIC_RELEASE, __HIP_MEMORY_SCOPE_AGENT);
        }
    } else {
        // ---------------- consumer: wait for b's 8 partials, broadcast ----------------
        const int bid2 = bid - 256;          // 0..8191
        const int bo   = bid2 >> 3;          // 0..1023
        const int oct  = bid2 & 7;
        const int b    = bo >> 5;
        const int o    = bo & 31;

        if (tid == 0) {
            const unsigned* f = wsu + FLAG_OFF + b * 8;
            for (int c = 0; c < 8; ++c)
                while (__hip_atomic_load(f + c, __ATOMIC_ACQUIRE,
                                         __HIP_MEMORY_SCOPE_AGENT) != MAGIC)
                    __builtin_amdgcn_s_sleep(15);
        }
        __syncthreads();

        const float* p = ws + PART_OFF + b * 8 * 32 + o;
        float sval = 0.f;
#pragma unroll
        for (int c = 0; c < 8; ++c)
            sval += __hip_atomic_load(p + c * 32, __ATOMIC_RELAXED,
                                      __HIP_MEMORY_SCOPE_AGENT);

        vf4 v = (vf4){sval, sval, sval, sval};
        vf4* __restrict__ out4 =
            (vf4*)out + (size_t)bo * 65536 + (size_t)oct * 8192 + tid;
#pragma unroll
        for (int j = 0; j < 16; ++j)
            __builtin_nontemporal_store(v, out4 + j * 512);
    }
}

extern "C" void kernel_launch(void* const* d_in, const int* in_sizes, int n_in,
                              void* d_out, int out_size, void* d_ws, size_t ws_size,
                              hipStream_t stream) {
    const float* x     = (const float*)d_in[0];
    const float* w_col = (const float*)d_in[1];
    const float* b_col = (const float*)d_in[2];
    const float* w_row = (const float*)d_in[3];
    const float* b_row = (const float*)d_in[4];
    float* out = (float*)d_out;
    float* ws  = (float*)d_ws;

    hipLaunchKernelGGL(k_prep, dim3(128), dim3(256), 0, stream, w_col, w_row, ws);
    hipLaunchKernelGGL(k_mega, dim3(8448), dim3(512), 0, stream, x, b_col, b_row, ws, out);
}

// Round 7
// 1104.211 us; speedup vs baseline: 1.3327x; 1.3327x over previous
//
#include <hip/hip_runtime.h>

#define Bn 32
#define Kn 512
#define Cn 32

typedef float vf4 __attribute__((ext_vector_type(4)));

// ws layout (float offsets)
#define WTC_OFF   0          // 16384: w_col transposed  wTc[k*32+o]
#define WTR_OFF   16384      // 16384: w_row transposed
#define PART_OFF  32768      // 32*8*32: part[b][chunk][o] (bias folded in per-chunk)

// ---------------- k0: transpose weights to k-major ----------------
__global__ void k_prep(const float* __restrict__ w_col,
                       const float* __restrict__ w_row,
                       float* __restrict__ ws) {
    int idx = blockIdx.x * 256 + threadIdx.x;          // 0..32767
    int which = idx >> 14;                             // 0: col, 1: row
    int e = idx & 16383;
    int o = e & 31, k = e >> 5;
    const float* src = which ? w_row : w_col;
    float* dst = ws + (which ? WTR_OFF : WTC_OFF);
    dst[e] = src[o * Kn + k];
}

// ---------------- k1: fused col/row GEMMs + per-chunk dot partial ----------------
// grid (8 t-chunks, 32 b) = 256 blocks × 512 threads (8 waves) → 8 waves/CU.
// wave w: phase = w>>2 (0=col, 1=row), kh = w&3 (k-quarter); lane = t (0..63).
// k is wave-uniform ⇒ all weight reads are SGPR s_loads (round-4 win).
// Output: part[b][chunk][o] = Σ_{t∈chunk} (col+bc)(row+br) — plain stores,
// no atomics; the kernel boundary orders it before k_broadcast.
__global__ __launch_bounds__(512) void k_fused(
    const float* __restrict__ x,      // [B][K][K]
    const float* __restrict__ bcol,
    const float* __restrict__ brow,
    float* __restrict__ ws) {
    const int chunk = blockIdx.x;     // 0..7
    const int b     = blockIdx.y;     // 0..31
    const int t0  = chunk * 64;
    const int tid = threadIdx.x;
    const int t   = tid & 63;                                   // lane
    const int wv  = __builtin_amdgcn_readfirstlane(tid >> 6);   // 0..7
    const int phase = wv >> 2;
    const int kh    = wv & 3;

    __shared__ float buf[8][64 * 33]; // 67.6 KB
    __shared__ float red2[16 * 33];

    const float* __restrict__ xb = x + b * (Kn * Kn);

    float acc[32];
#pragma unroll
    for (int o = 0; o < 32; ++o) acc[o] = 0.f;

    if (phase == 0) {
        // col[t,o] = sum_k x[t0+t][k] * wTc[k][o] — per-thread contiguous rows
        const float4* __restrict__ xr = (const float4*)(xb + (t0 + t) * Kn) + kh * 32;
        const float* __restrict__ wk = ws + WTC_OFF + kh * 128 * 32;
#pragma unroll 2
        for (int j = 0; j < 32; ++j) {                 // 32 float4 = 128 k
            float4 v = xr[j];
            const float* __restrict__ w0 = wk + j * 128;   // uniform → s_load
#pragma unroll
            for (int o = 0; o < 32; ++o) acc[o] = fmaf(v.x, w0[o],      acc[o]);
#pragma unroll
            for (int o = 0; o < 32; ++o) acc[o] = fmaf(v.y, w0[32 + o], acc[o]);
#pragma unroll
            for (int o = 0; o < 32; ++o) acc[o] = fmaf(v.z, w0[64 + o], acc[o]);
#pragma unroll
            for (int o = 0; o < 32; ++o) acc[o] = fmaf(v.w, w0[96 + o], acc[o]);
        }
    } else {
        // row[t,o] = sum_k x[k][t0+t] * wTr[k][o] — lane-contiguous column reads
        const float* __restrict__ wr = ws + WTR_OFF;
        const int kb = kh * 128;
#pragma unroll 4
        for (int k = 0; k < 128; ++k) {
            float xv = xb[(kb + k) * Kn + t0 + t];
            const float* __restrict__ w = wr + (kb + k) * 32;  // uniform → s_load
#pragma unroll
            for (int o = 0; o < 32; ++o) acc[o] = fmaf(xv, w[o], acc[o]);
        }
    }

    // park all 8 wave-accumulators in LDS ((33t+o)%32 = (t+o)%32, clean)
    {
        float* __restrict__ my = buf[wv] + t * 33;
#pragma unroll
        for (int o = 0; o < 32; ++o) my[o] = acc[o];
    }
    __syncthreads();

    // product-reduce: o = tid&31, g = tid>>5 covers 4 t each
    const int o = tid & 31, g = tid >> 5;            // g: 0..15
    const float bc = bcol[o], br = brow[o];
    float sum = 0.f;
#pragma unroll
    for (int j = 0; j < 4; ++j) {
        const int tt = g * 4 + j;
        const int a  = tt * 33 + o;
        float c = buf[0][a] + buf[1][a] + buf[2][a] + buf[3][a] + bc;
        float r = buf[4][a] + buf[5][a] + buf[6][a] + buf[7][a] + br;
        sum = fmaf(c, r, sum);
    }
    red2[g * 33 + o] = sum;
    __syncthreads();
    if (tid < 32) {
        float s = 0.f;
#pragma unroll
        for (int j = 0; j < 16; ++j) s += red2[j * 33 + tid];
        ws[PART_OFF + (b * 8 + chunk) * 32 + tid] = s;   // plain store, no atomic
    }
}

// ---------------- k2: sum 8 partials, broadcast to (B,C,512,512) ----------------
// 16384 blocks × 256 threads × 16 float4 = 1 GiB, fully coalesced nt stores.
// The 8 partial reads are block-uniform → scalar s_loads, negligible.
__global__ __launch_bounds__(256) void k_broadcast(const float* __restrict__ ws,
                                                   float* __restrict__ out) {
    const int bo   = blockIdx.x >> 4;            // 0..1023 = b*32+o
    const int part = blockIdx.x & 15;
    const int b    = bo >> 5;
    const int o    = bo & 31;
    const float* __restrict__ p = ws + PART_OFF + b * 8 * 32 + o;
    float sval = 0.f;
#pragma unroll
    for (int c = 0; c < 8; ++c) sval += p[c * 32];   // uniform → s_load
    vf4 v = (vf4){sval, sval, sval, sval};
    vf4* __restrict__ out4 =
        (vf4*)out + (size_t)bo * 65536 + (size_t)part * 4096 + threadIdx.x;
#pragma unroll
    for (int j = 0; j < 16; ++j)
        __builtin_nontemporal_store(v, out4 + j * 256);
}

extern "C" void kernel_launch(void* const* d_in, const int* in_sizes, int n_in,
                              void* d_out, int out_size, void* d_ws, size_t ws_size,
                              hipStream_t stream) {
    const float* x     = (const float*)d_in[0];
    const float* w_col = (const float*)d_in[1];
    const float* b_col = (const float*)d_in[2];
    const float* w_row = (const float*)d_in[3];
    const float* b_row = (const float*)d_in[4];
    float* out = (float*)d_out;
    float* ws  = (float*)d_ws;

    hipLaunchKernelGGL(k_prep, dim3(128), dim3(256), 0, stream, w_col, w_row, ws);
    hipLaunchKernelGGL(k_fused, dim3(8, 32), dim3(512), 0, stream, x, b_col, b_row, ws);
    hipLaunchKernelGGL(k_broadcast, dim3(16384), dim3(256), 0, stream, ws, out);
}